// Round 1
// baseline (2738.930 us; speedup 1.0000x reference)
//
#include <hip/hip_runtime.h>

#define NPIX   1024   // 32*32
#define NEH    992    // horizontal edges 32*31
#define NEDGE  1984   // + vertical 31*32
#define SORTN  2048
#define CHUNK  32
#define NMERGE 1023   // grid is connected -> exactly NPIX-1 merges

__device__ __forceinline__ void edge_ab(int e, int& a, int& b) {
    if (e < NEH) { int y = e / 31; int x = e - y * 31; a = y * 32 + x; b = a + 1; }
    else         { int ev = e - NEH; a = ev; b = ev + 32; }
}

__global__ __launch_bounds__(256, 1)
void malis_loss_kernel(const float* __restrict__ t_glob,
                       const float* __restrict__ p_glob,
                       float* __restrict__ out) {
    const int tid  = threadIdx.x;
    const int wg   = blockIdx.x;
    const int bat  = wg >> 6;          // 64 tiles per batch image
    const int tile = wg & 63;
    const int tr = tile >> 3, tc = tile & 7;

    __shared__ float          pT[NPIX];
    __shared__ unsigned char  bg[NPIX];
    __shared__ unsigned short lab[NPIX];
    __shared__ unsigned int   cnt[NPIX];
    __shared__ unsigned short pixLab[NPIX];
    __shared__ unsigned long long keys[SORTN];
    __shared__ unsigned short order[NEDGE];
    __shared__ unsigned short parent[NPIX];
    __shared__ unsigned short sizeL[NPIX];
    __shared__ unsigned short mRa[NMERGE];
    __shared__ unsigned short mRb[NMERGE];
    __shared__ unsigned short mEd[NMERGE];
    __shared__ unsigned int   sAsB[NMERGE];
    __shared__ unsigned int   commonW[NMERGE];
    __shared__ unsigned char  hasLab[NPIX];
    __shared__ unsigned short cc[NPIX * CHUNK];   // 64 KB count matrix (chunked)
    __shared__ int   flagSh, kprimeSh, mCountSh;
    __shared__ unsigned wsumSh;
    __shared__ float lossSh;

    // ---- load tile: pred values + background mask (t == 0) ----
    for (int i = tid; i < NPIX; i += 256) {
        int y = i >> 5, x = i & 31;
        int gidx = bat * 65536 + (tr * 32 + y) * 256 + (tc * 32 + x);
        pT[i] = p_glob[gidx];
        bg[i] = (t_glob[gidx] == 0.0f) ? 1 : 0;
    }
    __syncthreads();

    // ---- connected components of background (4-conn), min-index propagation ----
    for (int i = tid; i < NPIX; i += 256)
        lab[i] = bg[i] ? (unsigned short)i : (unsigned short)0xFFFF;
    __syncthreads();
    while (true) {
        if (tid == 0) flagSh = 0;
        __syncthreads();
        for (int i = tid; i < NPIX; i += 256) {
            if (!bg[i]) continue;
            int y = i >> 5, x = i & 31;
            unsigned v = lab[i];
            if (x > 0)  v = min(v, (unsigned)lab[i - 1]);
            if (x < 31) v = min(v, (unsigned)lab[i + 1]);
            if (y > 0)  v = min(v, (unsigned)lab[i - 32]);
            if (y < 31) v = min(v, (unsigned)lab[i + 32]);
            if (v < (unsigned)lab[i]) { lab[i] = (unsigned short)v; flagSh = 1; }
        }
        __syncthreads();
        if (flagSh == 0) break;
        __syncthreads();   // protect flag read vs next iteration's reset
    }

    // ---- per-label pixel counts; compact ids only for labels with >=2 px ----
    for (int i = tid; i < NPIX; i += 256) cnt[i] = 0;
    if (tid == 0) kprimeSh = 0;
    __syncthreads();
    for (int i = tid; i < NPIX; i += 256)
        if (bg[i]) atomicAdd(&cnt[lab[i]], 1u);
    __syncthreads();
    for (int i = tid; i < NPIX; i += 256) {
        if (bg[i] && (int)lab[i] == i) {
            unsigned id = (cnt[i] >= 2) ? (unsigned)atomicAdd(&kprimeSh, 1) : 0xFFFFu;
            cnt[i] = id;   // representative slot now holds compact id (or 0xFFFF)
        }
    }
    __syncthreads();
    for (int i = tid; i < NPIX; i += 256)
        pixLab[i] = bg[i] ? (unsigned short)cnt[lab[i]] : (unsigned short)0xFFFF;
    __syncthreads();
    const int K = kprimeSh;   // # labels that can contribute to 'common'

    for (int sgn = 0; sgn < 2; sgn++) {
        // ---- sort keys: descending cost, ties -> ascending edge index ----
        for (int k = tid; k < SORTN; k += 256) {
            unsigned long long key = 0ULL;
            if (k < NEDGE) {
                int a, b; edge_ab(k, a, b);
                float cost = pT[a] + pT[b];
                int nfg = (int)(!bg[a]) + (int)(!bg[b]);   // raw gt = 20*nfg
                if (sgn == 0) { if (nfg == 2) cost = 20.0f; }   // costs_n[gt>20]=20
                else          { if (nfg == 0) cost = 0.0f;  }   // costs_p[gt<10]=0
                key = ((unsigned long long)__float_as_uint(cost) << 16)
                    | (unsigned long long)(0xFFFFu - (unsigned)k);
            }
            keys[k] = key;   // pads sort last (key 0 < any real key)
        }
        __syncthreads();
        // bitonic sort, descending
        for (int kk = 2; kk <= SORTN; kk <<= 1) {
            for (int jj = kk >> 1; jj > 0; jj >>= 1) {
                for (int i = tid; i < SORTN; i += 256) {
                    int ixj = i ^ jj;
                    if (ixj > i) {
                        unsigned long long A = keys[i], Bv = keys[ixj];
                        bool descBlk = ((i & kk) == 0);
                        if ((A < Bv) == descBlk) { keys[i] = Bv; keys[ixj] = A; }
                    }
                }
                __syncthreads();
            }
        }
        for (int k = tid; k < NEDGE; k += 256)
            order[k] = (unsigned short)(0xFFFFu - (unsigned)(keys[k] & 0xFFFFULL));
        for (int i = tid; i < NPIX; i += 256) {
            parent[i] = (unsigned short)i;
            sizeL[i]  = bg[i];
        }
        __syncthreads();

        // ---- phase 1: serial Kruskal, record merge sequence ----
        if (tid == 0) {
            int m = 0;
            for (int k = 0; k < NEDGE; k++) {
                int e = order[k];
                int a, b; edge_ab(e, a, b);
                int ra = a;
                while (parent[ra] != ra) { parent[ra] = parent[parent[ra]]; ra = parent[ra]; }
                int rb = b;
                while (parent[rb] != rb) { parent[rb] = parent[parent[rb]]; rb = parent[rb]; }
                if (ra != rb) {
                    mRa[m] = (unsigned short)ra;
                    mRb[m] = (unsigned short)rb;
                    mEd[m] = (unsigned short)e;
                    sAsB[m] = (unsigned)sizeL[ra] * (unsigned)sizeL[rb];
                    sizeL[rb] = (unsigned short)(sizeL[rb] + sizeL[ra]);
                    parent[ra] = (unsigned short)rb;
                    m++;
                }
            }
            mCountSh = m;
        }
        __syncthreads();
        const int M = mCountSh;

        for (int j = tid; j < M; j += 256) commonW[j] = 0;
        __syncthreads();

        // ---- phase 2: chunked dense replay (32 labels / pass) ----
        for (int base = 0; base < K; base += CHUNK) {
            for (int i = tid; i < (NPIX * CHUNK) / 2; i += 256)
                ((unsigned int*)cc)[i] = 0;
            for (int i = tid; i < NPIX; i += 256) hasLab[i] = 0;
            __syncthreads();
            for (int i = tid; i < NPIX; i += 256) {
                unsigned pl = pixLab[i];
                if (pl != 0xFFFFu && pl >= (unsigned)base && pl < (unsigned)(base + CHUNK)) {
                    cc[i * CHUNK + (pl - base)] = 1;
                    hasLab[i] = 1;
                }
            }
            __syncthreads();
            if (tid < 64) {   // wave 0 replays serially; lanes = label columns
                const int lane = tid;
                for (int j = 0; j < M; j++) {
                    int ra = mRa[j];
                    if (hasLab[ra]) {
                        int rb = mRb[j];
                        unsigned ca = (lane < CHUNK) ? (unsigned)cc[ra * CHUNK + lane] : 0u;
                        if (!hasLab[rb]) {
                            if (lane < CHUNK) cc[rb * CHUNK + lane] = (unsigned short)ca;
                            if (lane == 0) hasLab[rb] = 1;
                        } else {
                            unsigned cb = (lane < CHUNK) ? (unsigned)cc[rb * CHUNK + lane] : 0u;
                            if (lane < CHUNK) cc[rb * CHUNK + lane] = (unsigned short)(ca + cb);
                            unsigned prod = ca * cb;
                            prod += __shfl_xor(prod, 1, 32);
                            prod += __shfl_xor(prod, 2, 32);
                            prod += __shfl_xor(prod, 4, 32);
                            prod += __shfl_xor(prod, 8, 32);
                            prod += __shfl_xor(prod, 16, 32);
                            if (lane == 0) commonW[j] += prod;
                        }
                    }
                }
            }
            __syncthreads();
        }

        // ---- normalize + mask + loss ----
        if (tid == 0) { wsumSh = 0; lossSh = 0.0f; }
        __syncthreads();
        unsigned wloc = 0;
        for (int j = tid; j < M; j += 256)
            wloc += (sgn == 0) ? (sAsB[j] - commonW[j]) : commonW[j];
        if (wloc) atomicAdd(&wsumSh, wloc);
        __syncthreads();
        const unsigned wsum = wsumSh;
        if (wsum > 0) {   // block-uniform
            const double inv = 1.0 / (double)wsum;
            float lloc = 0.0f;
            for (int j = tid; j < M; j += 256) {
                unsigned w = (sgn == 0) ? (sAsB[j] - commonW[j]) : commonW[j];
                if (!w) continue;
                int e = mEd[j];
                int a, b; edge_ab(e, a, b);
                int nfg = (int)(!bg[a]) + (int)(!bg[b]);
                bool keep = (sgn == 0) ? (nfg == 0) : (nfg >= 1);
                if (!keep) continue;
                float wn = (float)((double)w * inv);
                float fa, fb;
                if (sgn == 0) { fa = pT[a] * pT[a];            fb = pT[b] * pT[b]; }
                else { float da = 20.0f - pT[a], db = 20.0f - pT[b]; fa = da * da; fb = db * db; }
                lloc += wn * (fa + fb);
            }
            if (lloc != 0.0f) atomicAdd(&lossSh, lloc);
            __syncthreads();
            if (tid == 0 && lossSh != 0.0f) atomicAdd(out, lossSh);
        }
        __syncthreads();   // arrays reused by next sign
    }
}

extern "C" void kernel_launch(void* const* d_in, const int* in_sizes, int n_in,
                              void* d_out, int out_size, void* d_ws, size_t ws_size,
                              hipStream_t stream) {
    const float* y_true = (const float*)d_in[0];
    const float* y_pred = (const float*)d_in[1];
    float* out = (float*)d_out;
    const int B = in_sizes[0] / (256 * 256);
    hipMemsetAsync(d_out, 0, (size_t)out_size * sizeof(float), stream);
    hipLaunchKernelGGL(malis_loss_kernel, dim3(B * 64), dim3(256), 0, stream,
                       y_true, y_pred, out);
}

// Round 2
// 1370.374 us; speedup vs baseline: 1.9987x; 1.9987x over previous
//
#include <hip/hip_runtime.h>

#define NPIX   1024   // 32*32
#define NEH    992    // horizontal edges 32*31
#define NEDGE  1984   // + vertical 31*32
#define SORTN  2048
#define CHUNK  8      // labels per phase-2 pass
#define NMERGE 1023   // grid is connected -> exactly NPIX-1 merges
#define NIL    0xFFFFu

__device__ __forceinline__ void edge_ab(int e, int& a, int& b) {
    if (e < NEH) { int y = e / 31; int x = e - y * 31; a = y * 32 + x; b = a + 1; }
    else         { int ev = e - NEH; a = ev; b = ev + 32; }
}

__device__ __forceinline__ uint4 add4(uint4 x, uint4 y) {
    return make_uint4(x.x + y.x, x.y + y.y, x.z + y.z, x.w + y.w);   // u16 SWAR safe (counts <= 1024)
}
__device__ __forceinline__ uint4 sub4(uint4 x, uint4 y) {
    return make_uint4(x.x - y.x, x.y - y.y, x.z - y.z, x.w - y.w);   // per-u16 diff >= 0 -> no borrow
}

__global__ __launch_bounds__(256, 2)
void malis_loss_kernel(const float* __restrict__ t_glob,
                       const float* __restrict__ p_glob,
                       float* __restrict__ out) {
    const int tid  = threadIdx.x;
    const int wg   = blockIdx.x;
    const int sgn  = wg & 1;
    const int tileId = wg >> 1;
    const int bat  = tileId >> 6;
    const int tile = tileId & 63;
    const int tr = tile >> 3, tc = tile & 7;

    __shared__ float          pT[NPIX];                 // 4096
    __shared__ unsigned char  bgS[NPIX];                // 1024
    __shared__ unsigned short pixLab[NPIX];             // 2048
    __shared__ unsigned short parentS[NPIX];            // 2048
    __shared__ unsigned short nextS[NPIX];              // 2048
    __shared__ unsigned short headS[NPIX];              // 2048
    __shared__ unsigned short tailS[NPIX];              // 2048
    __shared__ unsigned short szAllS[NPIX];             // 2048
    __shared__ unsigned short szLabS[NPIX];             // 2048
    __shared__ unsigned short posS[NPIX];               // 2048
    __shared__ unsigned short orderS[NEDGE];            // 3968
    __shared__ unsigned short mHA[NMERGE];              // heads / sizes / edge per merge
    __shared__ unsigned short mHB[NMERGE];
    __shared__ unsigned short mSzA[NMERGE];
    __shared__ unsigned short mSzB[NMERGE];
    __shared__ unsigned short mEd[NMERGE];              // 5*2046 = 10230
    __shared__ unsigned int   mSaSb[NMERGE];            // 4092
    __shared__ unsigned int   commonW[NMERGE];          // 4092
    __shared__ __align__(16) unsigned long long big[2564];  // 20512 B arena: CCL | keys | ranking | prefix P
    __shared__ int   flagSh, kprimeSh, mCountSh;
    __shared__ unsigned wsumSh;
    __shared__ float lossSh;

    // ---- load tile ----
    for (int i = tid; i < NPIX; i += 256) {
        int y = i >> 5, x = i & 31;
        int gidx = bat * 65536 + (tr * 32 + y) * 256 + (tc * 32 + x);
        pT[i] = p_glob[gidx];
        bgS[i] = (t_glob[gidx] == 0.0f) ? 1 : 0;
    }
    __syncthreads();

    // ---- CCL of background via alternating row/col min-sweeps ----
    unsigned short* labS = (unsigned short*)big;                       // [0,2048)
    unsigned int*   cntS = (unsigned int*)(((char*)big) + 2048);       // [2048,6144)
    for (int i = tid; i < NPIX; i += 256)
        labS[i] = bgS[i] ? (unsigned short)i : (unsigned short)NIL;
    __syncthreads();
    while (true) {
        if (tid == 0) flagSh = 0;
        __syncthreads();
        if (tid < 32) {   // row sweeps, y = tid
            int y = tid;
            unsigned run = NIL;
            for (int x = 0; x < 32; x++) {
                int i = y * 32 + x;
                if (!bgS[i]) { run = NIL; continue; }
                unsigned v = min(run, (unsigned)labS[i]);
                if (v < (unsigned)labS[i]) { labS[i] = (unsigned short)v; flagSh = 1; }
                run = v;
            }
            run = NIL;
            for (int x = 31; x >= 0; x--) {
                int i = y * 32 + x;
                if (!bgS[i]) { run = NIL; continue; }
                unsigned v = min(run, (unsigned)labS[i]);
                if (v < (unsigned)labS[i]) { labS[i] = (unsigned short)v; flagSh = 1; }
                run = v;
            }
        }
        __syncthreads();
        if (tid < 32) {   // col sweeps, x = tid
            int x = tid;
            unsigned run = NIL;
            for (int y = 0; y < 32; y++) {
                int i = y * 32 + x;
                if (!bgS[i]) { run = NIL; continue; }
                unsigned v = min(run, (unsigned)labS[i]);
                if (v < (unsigned)labS[i]) { labS[i] = (unsigned short)v; flagSh = 1; }
                run = v;
            }
            run = NIL;
            for (int y = 31; y >= 0; y--) {
                int i = y * 32 + x;
                if (!bgS[i]) { run = NIL; continue; }
                unsigned v = min(run, (unsigned)labS[i]);
                if (v < (unsigned)labS[i]) { labS[i] = (unsigned short)v; flagSh = 1; }
                run = v;
            }
        }
        __syncthreads();
        if (flagSh == 0) break;
        __syncthreads();
    }

    // ---- compact labels: only components with >=2 px can contribute to 'common' ----
    for (int i = tid; i < NPIX; i += 256) cntS[i] = 0;
    if (tid == 0) kprimeSh = 0;
    __syncthreads();
    for (int i = tid; i < NPIX; i += 256)
        if (bgS[i]) atomicAdd(&cntS[labS[i]], 1u);
    __syncthreads();
    for (int i = tid; i < NPIX; i += 256) {
        if (bgS[i] && (int)labS[i] == i) {
            unsigned id = (cntS[i] >= 2) ? (unsigned)atomicAdd(&kprimeSh, 1) : NIL;
            cntS[i] = id;
        }
    }
    __syncthreads();
    for (int i = tid; i < NPIX; i += 256)
        pixLab[i] = bgS[i] ? (unsigned short)cntS[labS[i]] : (unsigned short)NIL;
    __syncthreads();
    const int K = kprimeSh;

    // ---- sort keys: descending cost, ties -> ascending edge index ----
    unsigned long long* keys = big;
    for (int k = tid; k < SORTN; k += 256) {
        unsigned long long key = 0ULL;
        if (k < NEDGE) {
            int a, b; edge_ab(k, a, b);
            float cost = pT[a] + pT[b];
            int nfg = (int)(!bgS[a]) + (int)(!bgS[b]);
            if (sgn == 0) { if (nfg == 2) cost = 20.0f; }
            else          { if (nfg == 0) cost = 0.0f;  }
            key = ((unsigned long long)__float_as_uint(cost) << 16)
                | (unsigned long long)(0xFFFFu - (unsigned)k);
        }
        keys[k] = key;
    }
    __syncthreads();
    for (int kk = 2; kk <= SORTN; kk <<= 1) {
        for (int jj = kk >> 1; jj > 0; jj >>= 1) {
            for (int i = tid; i < SORTN; i += 256) {
                int ixj = i ^ jj;
                if (ixj > i) {
                    unsigned long long A = keys[i], Bv = keys[ixj];
                    bool descBlk = ((i & kk) == 0);
                    if ((A < Bv) == descBlk) { keys[i] = Bv; keys[ixj] = A; }
                }
            }
            __syncthreads();
        }
    }
    for (int k = tid; k < NEDGE; k += 256)
        orderS[k] = (unsigned short)(0xFFFFu - (unsigned)(keys[k] & 0xFFFFULL));
    for (int i = tid; i < NPIX; i += 256) {
        parentS[i] = (unsigned short)i;
        headS[i] = tailS[i] = (unsigned short)i;
        szAllS[i] = 1;
        szLabS[i] = bgS[i];
        nextS[i]  = (unsigned short)NIL;
    }
    __syncthreads();

    // ---- serial Kruskal with list concat (records merge ranges implicitly via heads) ----
    if (tid == 0) {
        int m = 0;
        for (int k = 0; k < NEDGE; k++) {
            int e = orderS[k];
            int a, b; edge_ab(e, a, b);
            int ra = a, rb = b;
            while (true) {                       // interleaved path-splitting finds
                int pa = parentS[ra];
                int pb = parentS[rb];
                bool fa = (pa == ra), fb = (pb == rb);
                if (fa && fb) break;
                if (!fa) { int ga = parentS[pa]; parentS[ra] = (unsigned short)ga; ra = pa; }
                if (!fb) { int gb = parentS[pb]; parentS[rb] = (unsigned short)gb; rb = pb; }
            }
            if (ra != rb) {
                mHA[m] = headS[ra];
                mHB[m] = headS[rb];
                mSzA[m] = szAllS[ra];
                mSzB[m] = szAllS[rb];
                mSaSb[m] = (unsigned)szLabS[ra] * (unsigned)szLabS[rb];
                mEd[m] = (unsigned short)e;
                nextS[tailS[ra]] = headS[rb];    // new list = A ++ B
                headS[rb] = headS[ra];
                tailS[rb] = tailS[rb];
                szAllS[rb] = (unsigned short)(szAllS[rb] + szAllS[ra]);
                szLabS[rb] = (unsigned short)(szLabS[rb] + szLabS[ra]);
                parentS[ra] = (unsigned short)rb;
                m++;
            }
        }
        mCountSh = m;
    }
    __syncthreads();
    const int M = mCountSh;
    for (int j = tid; j < M; j += 256) commonW[j] = 0;

    // ---- parallel list ranking (Wyllie) -> posS ----
    unsigned short* n0 = (unsigned short*)big;
    unsigned short* n1 = n0 + 1024;
    unsigned short* d0 = n0 + 2048;
    unsigned short* d1 = n0 + 3072;
    for (int i = tid; i < NPIX; i += 256) { n0[i] = nextS[i]; d0[i] = 1; }
    __syncthreads();
    for (int s = 0; s < 10; s++) {
        unsigned short* sn = (s & 1) ? n1 : n0;
        unsigned short* sd = (s & 1) ? d1 : d0;
        unsigned short* dn = (s & 1) ? n0 : n1;
        unsigned short* dd = (s & 1) ? d0 : d1;
        for (int i = tid; i < NPIX; i += 256) {
            unsigned nx = sn[i];
            unsigned dv = sd[i];
            if (nx != NIL) { dv += sd[nx]; nx = sn[nx]; }
            dn[i] = (unsigned short)nx;
            dd[i] = (unsigned short)dv;
        }
        __syncthreads();
    }
    for (int i = tid; i < NPIX; i += 256)
        posS[i] = (unsigned short)(NPIX - (int)d0[i]);   // after 10 steps result is in buf0
    __syncthreads();

    // ---- phase 2: chunked label prefix sums over leaf order; parallel per-merge dots ----
    unsigned*       P32 = (unsigned*)big;                // rows: [1025][4] u32 (8 u16 labels SWAR)
    uint4*          P4  = (uint4*)big;
    unsigned*       scr = P32 + 4100;                    // 256 x uint4 block sums
    uint4*          S4  = (uint4*)scr;
    unsigned short* P16 = (unsigned short*)big;
    for (int base = 0; base < K; base += CHUNK) {
        for (int idx = tid; idx < 4100; idx += 256) P32[idx] = 0;
        __syncthreads();
        for (int i = tid; i < NPIX; i += 256) {
            unsigned l = pixLab[i];
            if (l != NIL && l >= (unsigned)base && l < (unsigned)(base + CHUNK))
                P16[(posS[i] + 1) * 8 + (l - base)] = 1;
        }
        __syncthreads();
        {   // blocked inclusive scan over rows 1..1024 (row 0 stays zero)
            int r0 = tid * 4 + 1;
            uint4 acc = P4[r0];
            for (int rr = r0 + 1; rr <= r0 + 3; rr++) { acc = add4(acc, P4[rr]); P4[rr] = acc; }
            S4[tid] = acc;
            __syncthreads();
            for (int s = 1; s < 256; s <<= 1) {
                uint4 v = S4[tid];
                uint4 o = make_uint4(0, 0, 0, 0);
                if (tid >= s) o = S4[tid - s];
                __syncthreads();
                S4[tid] = add4(v, o);
                __syncthreads();
            }
            if (tid > 0) {
                uint4 off = S4[tid - 1];
                for (int rr = r0; rr <= r0 + 3; rr++) P4[rr] = add4(P4[rr], off);
            }
        }
        __syncthreads();
        for (int j = tid; j < M; j += 256) {
            unsigned aS = posS[mHA[j]];
            unsigned bS = posS[mHB[j]];
            uint4 da = sub4(P4[aS + mSzA[j]], P4[aS]);
            uint4 db = sub4(P4[bS + mSzB[j]], P4[bS]);
            unsigned acc;
            acc  = (da.x & 0xFFFFu) * (db.x & 0xFFFFu) + (da.x >> 16) * (db.x >> 16);
            acc += (da.y & 0xFFFFu) * (db.y & 0xFFFFu) + (da.y >> 16) * (db.y >> 16);
            acc += (da.z & 0xFFFFu) * (db.z & 0xFFFFu) + (da.z >> 16) * (db.z >> 16);
            acc += (da.w & 0xFFFFu) * (db.w & 0xFFFFu) + (da.w >> 16) * (db.w >> 16);
            commonW[j] += acc;
        }
        __syncthreads();
    }

    // ---- normalize + mask + loss ----
    if (tid == 0) { wsumSh = 0; lossSh = 0.0f; }
    __syncthreads();
    unsigned wloc = 0;
    for (int j = tid; j < M; j += 256)
        wloc += (sgn == 0) ? (mSaSb[j] - commonW[j]) : commonW[j];
    if (wloc) atomicAdd(&wsumSh, wloc);
    __syncthreads();
    const unsigned wsum = wsumSh;
    if (wsum > 0) {
        const double inv = 1.0 / (double)wsum;
        float lloc = 0.0f;
        for (int j = tid; j < M; j += 256) {
            unsigned w = (sgn == 0) ? (mSaSb[j] - commonW[j]) : commonW[j];
            if (!w) continue;
            int e = mEd[j];
            int a, b; edge_ab(e, a, b);
            int nfg = (int)(!bgS[a]) + (int)(!bgS[b]);
            bool keep = (sgn == 0) ? (nfg == 0) : (nfg >= 1);
            if (!keep) continue;
            float wn = (float)((double)w * inv);
            float fa, fb;
            if (sgn == 0) { fa = pT[a] * pT[a];            fb = pT[b] * pT[b]; }
            else { float da = 20.0f - pT[a], db = 20.0f - pT[b]; fa = da * da; fb = db * db; }
            lloc += wn * (fa + fb);
        }
        if (lloc != 0.0f) atomicAdd(&lossSh, lloc);
        __syncthreads();
        if (tid == 0 && lossSh != 0.0f) atomicAdd(out, lossSh);
    }
}

extern "C" void kernel_launch(void* const* d_in, const int* in_sizes, int n_in,
                              void* d_out, int out_size, void* d_ws, size_t ws_size,
                              hipStream_t stream) {
    const float* y_true = (const float*)d_in[0];
    const float* y_pred = (const float*)d_in[1];
    float* out = (float*)d_out;
    const int B = in_sizes[0] / (256 * 256);
    hipMemsetAsync(d_out, 0, (size_t)out_size * sizeof(float), stream);
    hipLaunchKernelGGL(malis_loss_kernel, dim3(B * 64 * 2), dim3(256), 0, stream,
                       y_true, y_pred, out);
}

// Round 3
// 760.190 us; speedup vs baseline: 3.6030x; 1.8027x over previous
//
#include <hip/hip_runtime.h>

#define NPIX   1024   // 32*32
#define NEH    992    // horizontal edges 32*31
#define NEDGE  1984   // + vertical 31*32
#define SORTN  2048
#define CHUNK  8      // labels per phase-2 pass
#define NMERGE 1023   // grid is connected -> exactly NPIX-1 merges
#define NIL    0xFFFFu

__device__ __forceinline__ void edge_ab(int e, int& a, int& b) {
    if (e < NEH) { int y = e / 31; int x = e - y * 31; a = y * 32 + x; b = a + 1; }
    else         { int ev = e - NEH; a = ev; b = ev + 32; }
}

__device__ __forceinline__ uint4 add4(uint4 x, uint4 y) {
    return make_uint4(x.x + y.x, x.y + y.y, x.z + y.z, x.w + y.w);   // u16 SWAR safe (counts <= 1024)
}
__device__ __forceinline__ uint4 sub4(uint4 x, uint4 y) {
    return make_uint4(x.x - y.x, x.y - y.y, x.z - y.z, x.w - y.w);   // per-u16 diff >= 0 -> no borrow
}

__global__ __launch_bounds__(256, 2)
void malis_loss_kernel(const float* __restrict__ t_glob,
                       const float* __restrict__ p_glob,
                       float* __restrict__ out) {
    const int tid  = threadIdx.x;
    const int wg   = blockIdx.x;
    const int sgn  = wg & 1;
    const int tileId = wg >> 1;
    const int bat  = tileId >> 6;
    const int tile = tileId & 63;
    const int tr = tile >> 3, tc = tile & 7;

    __shared__ float          pT[NPIX];                 // 4096
    __shared__ unsigned char  bgS[NPIX];                // 1024
    __shared__ unsigned short pixLab[NPIX];             // 2048
    __shared__ unsigned short parentS[NPIX];            // 2048
    __shared__ unsigned short nextS[NPIX];              // 2048
    __shared__ unsigned long long nodeS[NPIX];          // 8192: head|tail|szAll|szLab packed u16x4
    __shared__ unsigned short posS[NPIX];               // 2048
    __shared__ unsigned short orderS[NEDGE];            // 3968
    __shared__ unsigned int   mRecA[NMERGE];            // headA<<16 | headB
    __shared__ unsigned int   mRecB[NMERGE];            // szAllA<<16 | szAllB
    __shared__ unsigned short mEd[NMERGE];
    __shared__ unsigned int   mSaSb[NMERGE];
    __shared__ unsigned int   commonW[NMERGE];
    __shared__ unsigned long long specS[64];            // per-batch speculative finds
    __shared__ __align__(16) unsigned long long big[2564];  // 20.5 KB arena: CCL | keys | ranking | prefix P
    __shared__ int   flagSh, kprimeSh, mCountSh;
    __shared__ unsigned wsumSh;
    __shared__ float lossSh;

    // ---- load tile ----
    for (int i = tid; i < NPIX; i += 256) {
        int y = i >> 5, x = i & 31;
        int gidx = bat * 65536 + (tr * 32 + y) * 256 + (tc * 32 + x);
        pT[i] = p_glob[gidx];
        bgS[i] = (t_glob[gidx] == 0.0f) ? 1 : 0;
    }
    __syncthreads();

    // ---- CCL of background via alternating row/col min-sweeps ----
    unsigned short* labS = (unsigned short*)big;
    unsigned int*   cntS = (unsigned int*)(((char*)big) + 2048);
    for (int i = tid; i < NPIX; i += 256)
        labS[i] = bgS[i] ? (unsigned short)i : (unsigned short)NIL;
    __syncthreads();
    while (true) {
        if (tid == 0) flagSh = 0;
        __syncthreads();
        if (tid < 32) {
            int y = tid;
            unsigned run = NIL;
            for (int x = 0; x < 32; x++) {
                int i = y * 32 + x;
                if (!bgS[i]) { run = NIL; continue; }
                unsigned v = min(run, (unsigned)labS[i]);
                if (v < (unsigned)labS[i]) { labS[i] = (unsigned short)v; flagSh = 1; }
                run = v;
            }
            run = NIL;
            for (int x = 31; x >= 0; x--) {
                int i = y * 32 + x;
                if (!bgS[i]) { run = NIL; continue; }
                unsigned v = min(run, (unsigned)labS[i]);
                if (v < (unsigned)labS[i]) { labS[i] = (unsigned short)v; flagSh = 1; }
                run = v;
            }
        }
        __syncthreads();
        if (tid < 32) {
            int x = tid;
            unsigned run = NIL;
            for (int y = 0; y < 32; y++) {
                int i = y * 32 + x;
                if (!bgS[i]) { run = NIL; continue; }
                unsigned v = min(run, (unsigned)labS[i]);
                if (v < (unsigned)labS[i]) { labS[i] = (unsigned short)v; flagSh = 1; }
                run = v;
            }
            run = NIL;
            for (int y = 31; y >= 0; y--) {
                int i = y * 32 + x;
                if (!bgS[i]) { run = NIL; continue; }
                unsigned v = min(run, (unsigned)labS[i]);
                if (v < (unsigned)labS[i]) { labS[i] = (unsigned short)v; flagSh = 1; }
                run = v;
            }
        }
        __syncthreads();
        if (flagSh == 0) break;
        __syncthreads();
    }

    // ---- compact labels: only components with >=2 px can contribute to 'common' ----
    for (int i = tid; i < NPIX; i += 256) cntS[i] = 0;
    if (tid == 0) kprimeSh = 0;
    __syncthreads();
    for (int i = tid; i < NPIX; i += 256)
        if (bgS[i]) atomicAdd(&cntS[labS[i]], 1u);
    __syncthreads();
    for (int i = tid; i < NPIX; i += 256) {
        if (bgS[i] && (int)labS[i] == i) {
            unsigned id = (cntS[i] >= 2) ? (unsigned)atomicAdd(&kprimeSh, 1) : NIL;
            cntS[i] = id;
        }
    }
    __syncthreads();
    for (int i = tid; i < NPIX; i += 256)
        pixLab[i] = bgS[i] ? (unsigned short)cntS[labS[i]] : (unsigned short)NIL;
    __syncthreads();
    const int K = kprimeSh;

    // ---- sort keys: descending cost, ties -> ascending edge index ----
    unsigned long long* keys = big;
    for (int k = tid; k < SORTN; k += 256) {
        unsigned long long key = 0ULL;
        if (k < NEDGE) {
            int a, b; edge_ab(k, a, b);
            float cost = pT[a] + pT[b];
            int nfg = (int)(!bgS[a]) + (int)(!bgS[b]);
            if (sgn == 0) { if (nfg == 2) cost = 20.0f; }
            else          { if (nfg == 0) cost = 0.0f;  }
            key = ((unsigned long long)__float_as_uint(cost) << 16)
                | (unsigned long long)(0xFFFFu - (unsigned)k);
        }
        keys[k] = key;
    }
    __syncthreads();
    for (int kk = 2; kk <= SORTN; kk <<= 1) {
        for (int jj = kk >> 1; jj > 0; jj >>= 1) {
            for (int i = tid; i < SORTN; i += 256) {
                int ixj = i ^ jj;
                if (ixj > i) {
                    unsigned long long A = keys[i], Bv = keys[ixj];
                    bool descBlk = ((i & kk) == 0);
                    if ((A < Bv) == descBlk) { keys[i] = Bv; keys[ixj] = A; }
                }
            }
            __syncthreads();
        }
    }
    for (int k = tid; k < NEDGE; k += 256)
        orderS[k] = (unsigned short)(0xFFFFu - (unsigned)(keys[k] & 0xFFFFULL));
    for (int i = tid; i < NPIX; i += 256) {
        parentS[i] = (unsigned short)i;
        nodeS[i] = ((unsigned long long)i << 48) | ((unsigned long long)i << 32)
                 | (1ULL << 16) | (unsigned long long)bgS[i];
        nextS[i] = (unsigned short)NIL;
    }
    __syncthreads();

    // ---- Kruskal: wave-parallel speculative finds + lane-0 serial confirm/merge ----
    if (tid < 64) {
        const int lane = tid;
        int m = 0;
        for (int kb = 0; kb < NEDGE; kb += 64) {      // 31 exact batches
            // spec phase: all 64 lanes find roots for their edge (path-halving)
            {
                int e = orderS[kb + lane];
                int a, b; edge_ab(e, a, b);
                unsigned ra = (unsigned)a, rb = (unsigned)b;
                while (true) {
                    unsigned pa = parentS[ra];
                    unsigned pb = parentS[rb];
                    if (pa == ra && pb == rb) break;
                    if (pa != ra) { unsigned ga = parentS[pa]; parentS[ra] = (unsigned short)ga; ra = ga; }
                    if (pb != rb) { unsigned gb = parentS[pb]; parentS[rb] = (unsigned short)gb; rb = gb; }
                }
                specS[lane] = ((unsigned long long)(unsigned)e << 32)
                            | ((unsigned long long)ra << 16) | rb;
            }
            __builtin_amdgcn_sched_barrier(0);
            asm volatile("s_waitcnt lgkmcnt(0)" ::: "memory");
            if (lane == 0) {
                unsigned long long cur = specS[0];
                for (int i = 0; i < 64; i++) {
                    unsigned long long nxt = (i < 63) ? specS[i + 1] : 0ULL;   // prefetch
                    unsigned ra = (unsigned)(cur >> 16) & 0xFFFFu;
                    unsigned rb = (unsigned)cur & 0xFFFFu;
                    if (ra != rb) {   // spec-equal => definitely connected, skip free
                        // resolve residual staleness (<= intra-batch merges)
                        unsigned pa = parentS[ra], pb = parentS[rb];
                        while (pa != ra || pb != rb) {
                            ra = pa; rb = pb;
                            pa = parentS[ra]; pb = parentS[rb];
                        }
                        if (ra != rb) {
                            unsigned e = (unsigned)(cur >> 32);
                            unsigned long long na = nodeS[ra], nb = nodeS[rb];
                            unsigned headA = (unsigned)(na >> 48);
                            unsigned tailA = (unsigned)(na >> 32) & 0xFFFFu;
                            unsigned szA   = (unsigned)(na >> 16) & 0xFFFFu;
                            unsigned slA   = (unsigned)na & 0xFFFFu;
                            unsigned headB = (unsigned)(nb >> 48);
                            unsigned tailB = (unsigned)(nb >> 32) & 0xFFFFu;
                            unsigned szB   = (unsigned)(nb >> 16) & 0xFFFFu;
                            unsigned slB   = (unsigned)nb & 0xFFFFu;
                            mRecA[m] = (headA << 16) | headB;
                            mRecB[m] = (szA << 16) | szB;
                            mSaSb[m] = slA * slB;
                            mEd[m]   = (unsigned short)e;
                            nextS[tailA] = (unsigned short)headB;   // list = A ++ B
                            nodeS[rb] = ((unsigned long long)headA << 48)
                                      | ((unsigned long long)tailB << 32)
                                      | ((unsigned long long)(szA + szB) << 16)
                                      | (unsigned long long)(slA + slB);
                            parentS[ra] = (unsigned short)rb;
                            m++;
                        }
                    }
                    cur = nxt;
                }
            }
            __builtin_amdgcn_sched_barrier(0);
            asm volatile("s_waitcnt lgkmcnt(0)" ::: "memory");
        }
        if (lane == 0) mCountSh = m;
    }
    __syncthreads();
    const int M = mCountSh;
    for (int j = tid; j < M; j += 256) commonW[j] = 0;

    // ---- parallel list ranking (Wyllie) -> posS ----
    unsigned short* n0 = (unsigned short*)big;
    unsigned short* n1 = n0 + 1024;
    unsigned short* d0 = n0 + 2048;
    unsigned short* d1 = n0 + 3072;
    for (int i = tid; i < NPIX; i += 256) { n0[i] = nextS[i]; d0[i] = 1; }
    __syncthreads();
    for (int s = 0; s < 10; s++) {
        unsigned short* sn = (s & 1) ? n1 : n0;
        unsigned short* sd = (s & 1) ? d1 : d0;
        unsigned short* dn = (s & 1) ? n0 : n1;
        unsigned short* dd = (s & 1) ? d0 : d1;
        for (int i = tid; i < NPIX; i += 256) {
            unsigned nx = sn[i];
            unsigned dv = sd[i];
            if (nx != NIL) { dv += sd[nx]; nx = sn[nx]; }
            dn[i] = (unsigned short)nx;
            dd[i] = (unsigned short)dv;
        }
        __syncthreads();
    }
    for (int i = tid; i < NPIX; i += 256)
        posS[i] = (unsigned short)(NPIX - (int)d0[i]);
    __syncthreads();

    // ---- phase 2: chunked label prefix sums over leaf order; parallel per-merge dots ----
    unsigned*       P32 = (unsigned*)big;                // [1025][4] u32 (8 u16 labels SWAR)
    uint4*          P4  = (uint4*)big;
    unsigned*       scr = P32 + 4100;
    uint4*          S4  = (uint4*)scr;
    unsigned short* P16 = (unsigned short*)big;
    for (int base = 0; base < K; base += CHUNK) {
        for (int idx = tid; idx < 4100; idx += 256) P32[idx] = 0;
        __syncthreads();
        for (int i = tid; i < NPIX; i += 256) {
            unsigned l = pixLab[i];
            if (l != NIL && l >= (unsigned)base && l < (unsigned)(base + CHUNK))
                P16[(posS[i] + 1) * 8 + (l - base)] = 1;
        }
        __syncthreads();
        {   // blocked inclusive scan over rows 1..1024 (row 0 stays zero)
            int r0 = tid * 4 + 1;
            uint4 acc = P4[r0];
            for (int rr = r0 + 1; rr <= r0 + 3; rr++) { acc = add4(acc, P4[rr]); P4[rr] = acc; }
            S4[tid] = acc;
            __syncthreads();
            if (tid < 64) {   // wave-0 shuffle scan of the 256 block sums
                uint4 s0 = S4[tid * 4], s1 = S4[tid * 4 + 1], s2 = S4[tid * 4 + 2], s3 = S4[tid * 4 + 3];
                uint4 t1 = add4(s0, s1), t2 = add4(t1, s2), t3 = add4(t2, s3);
                uint4 run = t3;
                #pragma unroll
                for (int d = 1; d < 64; d <<= 1) {
                    uint4 o;
                    o.x = __shfl_up(run.x, d, 64);
                    o.y = __shfl_up(run.y, d, 64);
                    o.z = __shfl_up(run.z, d, 64);
                    o.w = __shfl_up(run.w, d, 64);
                    if (tid >= d) run = add4(run, o);
                }
                uint4 off = sub4(run, t3);   // exclusive prefix of lane totals
                S4[tid * 4]     = add4(s0, off);
                S4[tid * 4 + 1] = add4(t1, off);
                S4[tid * 4 + 2] = add4(t2, off);
                S4[tid * 4 + 3] = add4(t3, off);
            }
            __syncthreads();
            if (tid > 0) {
                uint4 off = S4[tid - 1];
                for (int rr = r0; rr <= r0 + 3; rr++) P4[rr] = add4(P4[rr], off);
            }
        }
        __syncthreads();
        for (int j = tid; j < M; j += 256) {
            unsigned recA = mRecA[j], recB = mRecB[j];
            unsigned aS = posS[recA >> 16];
            unsigned bS = posS[recA & 0xFFFFu];
            uint4 da = sub4(P4[aS + (recB >> 16)], P4[aS]);
            uint4 db = sub4(P4[bS + (recB & 0xFFFFu)], P4[bS]);
            unsigned acc;
            acc  = (da.x & 0xFFFFu) * (db.x & 0xFFFFu) + (da.x >> 16) * (db.x >> 16);
            acc += (da.y & 0xFFFFu) * (db.y & 0xFFFFu) + (da.y >> 16) * (db.y >> 16);
            acc += (da.z & 0xFFFFu) * (db.z & 0xFFFFu) + (da.z >> 16) * (db.z >> 16);
            acc += (da.w & 0xFFFFu) * (db.w & 0xFFFFu) + (da.w >> 16) * (db.w >> 16);
            commonW[j] += acc;
        }
        __syncthreads();
    }

    // ---- normalize + mask + loss ----
    if (tid == 0) { wsumSh = 0; lossSh = 0.0f; }
    __syncthreads();
    unsigned wloc = 0;
    for (int j = tid; j < M; j += 256)
        wloc += (sgn == 0) ? (mSaSb[j] - commonW[j]) : commonW[j];
    if (wloc) atomicAdd(&wsumSh, wloc);
    __syncthreads();
    const unsigned wsum = wsumSh;
    if (wsum > 0) {
        const double inv = 1.0 / (double)wsum;
        float lloc = 0.0f;
        for (int j = tid; j < M; j += 256) {
            unsigned w = (sgn == 0) ? (mSaSb[j] - commonW[j]) : commonW[j];
            if (!w) continue;
            int e = mEd[j];
            int a, b; edge_ab(e, a, b);
            int nfg = (int)(!bgS[a]) + (int)(!bgS[b]);
            bool keep = (sgn == 0) ? (nfg == 0) : (nfg >= 1);
            if (!keep) continue;
            float wn = (float)((double)w * inv);
            float fa, fb;
            if (sgn == 0) { fa = pT[a] * pT[a];            fb = pT[b] * pT[b]; }
            else { float da = 20.0f - pT[a], db = 20.0f - pT[b]; fa = da * da; fb = db * db; }
            lloc += wn * (fa + fb);
        }
        if (lloc != 0.0f) atomicAdd(&lossSh, lloc);
        __syncthreads();
        if (tid == 0 && lossSh != 0.0f) atomicAdd(out, lossSh);
    }
}

extern "C" void kernel_launch(void* const* d_in, const int* in_sizes, int n_in,
                              void* d_out, int out_size, void* d_ws, size_t ws_size,
                              hipStream_t stream) {
    const float* y_true = (const float*)d_in[0];
    const float* y_pred = (const float*)d_in[1];
    float* out = (float*)d_out;
    const int B = in_sizes[0] / (256 * 256);
    hipMemsetAsync(d_out, 0, (size_t)out_size * sizeof(float), stream);
    hipLaunchKernelGGL(malis_loss_kernel, dim3(B * 64 * 2), dim3(256), 0, stream,
                       y_true, y_pred, out);
}

// Round 4
// 652.704 us; speedup vs baseline: 4.1963x; 1.1647x over previous
//
#include <hip/hip_runtime.h>

#define NPIX   1024   // 32*32
#define NEH    992    // horizontal edges 32*31
#define NEDGE  1984   // + vertical 31*32
#define SORTN  2048
#define CHUNK  8      // labels per phase-2 pass
#define NMERGE 1023   // grid is connected -> exactly NPIX-1 merges
#define NIL    0xFFFFu

__device__ __forceinline__ void edge_ab(int e, int& a, int& b) {
    if (e < NEH) { int y = e / 31; int x = e - y * 31; a = y * 32 + x; b = a + 1; }
    else         { int ev = e - NEH; a = ev; b = ev + 32; }
}

__device__ __forceinline__ uint4 add4(uint4 x, uint4 y) {
    return make_uint4(x.x + y.x, x.y + y.y, x.z + y.z, x.w + y.w);   // u16 SWAR safe (counts <= 1024)
}
__device__ __forceinline__ uint4 sub4(uint4 x, uint4 y) {
    return make_uint4(x.x - y.x, x.y - y.y, x.z - y.z, x.w - y.w);   // per-u16 diff >= 0 -> no borrow
}

__global__ __launch_bounds__(256, 2)
void malis_loss_kernel(const float* __restrict__ t_glob,
                       const float* __restrict__ p_glob,
                       float* __restrict__ out) {
    const int tid  = threadIdx.x;
    const int wg   = blockIdx.x;
    const int sgn  = wg & 1;
    const int tileId = wg >> 1;
    const int bat  = tileId >> 6;
    const int tile = tileId & 63;
    const int tr = tile >> 3, tc = tile & 7;

    __shared__ float          pT[NPIX];                 // 4096
    __shared__ unsigned char  bgS[NPIX];                // 1024
    __shared__ unsigned short pixLab[NPIX];             // 2048
    __shared__ unsigned short parentS[NPIX];            // 2048
    __shared__ unsigned short nextS[NPIX];              // 2048
    __shared__ unsigned long long nodeS[NPIX];          // 8192: head|tail|szAll|szLab packed u16x4
    __shared__ unsigned short posS[NPIX];               // 2048
    __shared__ unsigned short orderS[NEDGE];            // 3968
    __shared__ unsigned int   mRecA[NMERGE];            // headA<<16 | headB
    __shared__ unsigned int   mRecB[NMERGE];            // szAllA<<16 | szAllB
    __shared__ unsigned short mEd[NMERGE];
    __shared__ unsigned int   mSaSb[NMERGE];
    __shared__ unsigned int   commonW[NMERGE];
    __shared__ __align__(16) unsigned long long big[2564];  // 20.5 KB arena: CCL | keys | ranking | prefix P
    __shared__ int   kprimeSh, mCountSh;
    __shared__ unsigned wsumSh;
    __shared__ float lossSh;

    // ---- load tile ----
    for (int i = tid; i < NPIX; i += 256) {
        int y = i >> 5, x = i & 31;
        int gidx = bat * 65536 + (tr * 32 + y) * 256 + (tc * 32 + x);
        pT[i] = p_glob[gidx];
        bgS[i] = (t_glob[gidx] == 0.0f) ? 1 : 0;
    }
    __syncthreads();

    // ---- CCL of background: single-wave, register-SWAR row/col min-sweeps ----
    unsigned short* labS = (unsigned short*)big;
    unsigned int*   cntS = (unsigned int*)(((char*)big) + 2048);
    if (tid < 64) {
        const int lane = tid;
        if (lane < 32) {
            #pragma unroll
            for (int x = 0; x < 32; x++) {
                int i = lane * 32 + x;
                labS[i] = bgS[i] ? (unsigned short)i : (unsigned short)NIL;
            }
        }
        while (true) {
            bool changed = false;
            if (lane < 32) {
                // row sweep (lane = row), values in registers
                const int base = lane * 32;
                unsigned short v[32];
                #pragma unroll
                for (int x = 0; x < 32; x++) v[x] = labS[base + x];
                unsigned run = NIL;
                #pragma unroll
                for (int x = 0; x < 32; x++) {
                    unsigned val = v[x];
                    if (val == NIL) { run = NIL; }
                    else { unsigned nv = min(run, val); changed |= (nv != val); v[x] = (unsigned short)nv; run = nv; }
                }
                run = NIL;
                #pragma unroll
                for (int x = 31; x >= 0; x--) {
                    unsigned val = v[x];
                    if (val == NIL) { run = NIL; }
                    else { unsigned nv = min(run, val); changed |= (nv != val); v[x] = (unsigned short)nv; run = nv; }
                }
                #pragma unroll
                for (int x = 0; x < 32; x++) labS[base + x] = v[x];
            }
            // same-wave DS ops are in-order: col phase sees row writes
            if (lane < 32) {
                unsigned short c[32];
                #pragma unroll
                for (int k = 0; k < 32; k++) c[k] = labS[k * 32 + lane];
                unsigned run = NIL;
                #pragma unroll
                for (int k = 0; k < 32; k++) {
                    unsigned val = c[k];
                    if (val == NIL) { run = NIL; }
                    else { unsigned nv = min(run, val); changed |= (nv != val); c[k] = (unsigned short)nv; run = nv; }
                }
                run = NIL;
                #pragma unroll
                for (int k = 31; k >= 0; k--) {
                    unsigned val = c[k];
                    if (val == NIL) { run = NIL; }
                    else { unsigned nv = min(run, val); changed |= (nv != val); c[k] = (unsigned short)nv; run = nv; }
                }
                #pragma unroll
                for (int k = 0; k < 32; k++) labS[k * 32 + lane] = c[k];
            }
            if (!__any(changed)) break;
        }
    }
    __syncthreads();

    // ---- compact labels: only components with >=2 px can contribute to 'common' ----
    for (int i = tid; i < NPIX; i += 256) cntS[i] = 0;
    if (tid == 0) kprimeSh = 0;
    __syncthreads();
    for (int i = tid; i < NPIX; i += 256)
        if (bgS[i]) atomicAdd(&cntS[labS[i]], 1u);
    __syncthreads();
    for (int i = tid; i < NPIX; i += 256) {
        if (bgS[i] && (int)labS[i] == i) {
            unsigned id = (cntS[i] >= 2) ? (unsigned)atomicAdd(&kprimeSh, 1) : NIL;
            cntS[i] = id;
        }
    }
    __syncthreads();
    for (int i = tid; i < NPIX; i += 256)
        pixLab[i] = bgS[i] ? (unsigned short)cntS[labS[i]] : (unsigned short)NIL;
    __syncthreads();
    const int K = kprimeSh;

    // ---- sort keys: descending cost, ties -> ascending edge index ----
    unsigned long long* keys = big;
    for (int k = tid; k < SORTN; k += 256) {
        unsigned long long key = 0ULL;
        if (k < NEDGE) {
            int a, b; edge_ab(k, a, b);
            float cost = pT[a] + pT[b];
            int nfg = (int)(!bgS[a]) + (int)(!bgS[b]);
            if (sgn == 0) { if (nfg == 2) cost = 20.0f; }
            else          { if (nfg == 0) cost = 0.0f;  }
            key = ((unsigned long long)__float_as_uint(cost) << 16)
                | (unsigned long long)(0xFFFFu - (unsigned)k);
        }
        keys[k] = key;
    }
    __syncthreads();
    for (int kk = 2; kk <= SORTN; kk <<= 1) {
        for (int jj = kk >> 1; jj > 0; jj >>= 1) {
            for (int i = tid; i < SORTN; i += 256) {
                int ixj = i ^ jj;
                if (ixj > i) {
                    unsigned long long A = keys[i], Bv = keys[ixj];
                    bool descBlk = ((i & kk) == 0);
                    if ((A < Bv) == descBlk) { keys[i] = Bv; keys[ixj] = A; }
                }
            }
            __syncthreads();
        }
    }
    for (int k = tid; k < NEDGE; k += 256)
        orderS[k] = (unsigned short)(0xFFFFu - (unsigned)(keys[k] & 0xFFFFULL));
    for (int i = tid; i < NPIX; i += 256) {
        parentS[i] = (unsigned short)i;
        nodeS[i] = ((unsigned long long)i << 48) | ((unsigned long long)i << 32)
                 | (1ULL << 16) | (unsigned long long)bgS[i];
        nextS[i] = (unsigned short)NIL;
    }
    __syncthreads();

    // ---- Kruskal: wave-parallel spec finds + whole-wave pipelined confirm ----
    if (tid < 64) {
        const int lane = tid;
        int m = 0;
        for (int kb = 0; kb < NEDGE; kb += 64) {      // 31 exact batches
            // spec phase: all 64 lanes find roots for their edge (concurrent path-halving)
            int e = orderS[kb + lane];
            int a, b; edge_ab(e, a, b);
            unsigned ra = (unsigned)a, rb = (unsigned)b;
            while (true) {
                unsigned pa = parentS[ra];
                unsigned pb = parentS[rb];
                if (pa == ra && pb == rb) break;
                if (pa != ra) { unsigned ga = parentS[pa]; parentS[ra] = (unsigned short)ga; ra = ga; }
                if (pb != rb) { unsigned gb = parentS[pb]; parentS[rb] = (unsigned short)gb; rb = gb; }
            }
            unsigned long long spec = ((unsigned long long)(unsigned)e << 32)
                                    | ((unsigned long long)ra << 16) | (unsigned long long)rb;
            unsigned long long candm = __ballot(ra != rb);   // spec-equal => still connected => true skip

            // confirm: whole wave runs the serial chain redundantly (uniform);
            // one-candidate-ahead prefetch with register patching; lane0 commits.
            bool haveCur = false;
            unsigned cra = 0, crb = 0, ce = 0, cpa = 0, cpb = 0;
            unsigned long long cna = 0, cnb = 0;
            while (candm != 0ULL || haveCur) {
                bool haveNext = (candm != 0ULL);
                unsigned nra = 0, nrb = 0, ne = 0, npa = 0, npb = 0;
                unsigned long long nna = 0, nnb = 0;
                if (haveNext) {
                    int j = __ffsll((long long)candm) - 1;
                    candm &= candm - 1ULL;
                    unsigned long long sj = __shfl(spec, j);
                    ne  = (unsigned)(sj >> 32);
                    nra = (unsigned)(sj >> 16) & 0xFFFFu;
                    nrb = (unsigned)sj & 0xFFFFu;
                    npa = parentS[nra];          // 4 independent loads, one LDS round;
                    npb = parentS[nrb];          // latency hidden under current merge's VALU
                    nna = nodeS[nra];
                    nnb = nodeS[nrb];
                }
                if (haveCur) {
                    unsigned ra2 = cra, rb2 = crb;
                    unsigned long long na = cna, nb = cnb;
                    bool ok = true;
                    if (cpa != ra2 || cpb != rb2) {     // stale spec roots (earlier-in-batch merges)
                        unsigned r = cpa;
                        while (true) { unsigned p = parentS[r]; if (p == r) break; r = p; }
                        ra2 = r;
                        r = cpb;
                        while (true) { unsigned p = parentS[r]; if (p == r) break; r = p; }
                        rb2 = r;
                        if (ra2 == rb2) ok = false;
                        else { na = nodeS[ra2]; nb = nodeS[rb2]; }
                    }
                    if (ok) {
                        unsigned headA = (unsigned)(na >> 48);
                        unsigned tailA = (unsigned)(na >> 32) & 0xFFFFu;
                        unsigned szA   = (unsigned)(na >> 16) & 0xFFFFu;
                        unsigned slA   = (unsigned)na & 0xFFFFu;
                        unsigned headB = (unsigned)(nb >> 48);
                        unsigned tailB = (unsigned)(nb >> 32) & 0xFFFFu;
                        unsigned szB   = (unsigned)(nb >> 16) & 0xFFFFu;
                        unsigned slB   = (unsigned)nb & 0xFFFFu;
                        unsigned long long merged =
                              ((unsigned long long)headA << 48)
                            | ((unsigned long long)tailB << 32)
                            | ((unsigned long long)(szA + szB) << 16)
                            | (unsigned long long)(slA + slB);
                        if (lane == 0) {
                            mRecA[m] = (headA << 16) | headB;
                            mRecB[m] = (szA << 16) | szB;
                            mSaSb[m] = slA * slB;
                            mEd[m]   = (unsigned short)ce;
                            nextS[tailA] = (unsigned short)headB;   // list = A ++ B
                            nodeS[rb2]   = merged;
                            parentS[ra2] = (unsigned short)rb2;
                        }
                        m++;
                        if (haveNext) {   // idempotent register patch vs this merge's writes
                            if (nra == ra2) npa = rb2;
                            if (nrb == ra2) npb = rb2;
                            if (nra == rb2) nna = merged;
                            if (nrb == rb2) nnb = merged;
                        }
                    }
                }
                cra = nra; crb = nrb; ce = ne; cpa = npa; cpb = npb; cna = nna; cnb = nnb;
                haveCur = haveNext;
            }
        }
        if (lane == 0) mCountSh = m;
    }
    __syncthreads();
    const int M = mCountSh;
    for (int j = tid; j < M; j += 256) commonW[j] = 0;

    // ---- parallel list ranking (Wyllie) -> posS ----
    unsigned short* n0 = (unsigned short*)big;
    unsigned short* n1 = n0 + 1024;
    unsigned short* d0 = n0 + 2048;
    unsigned short* d1 = n0 + 3072;
    for (int i = tid; i < NPIX; i += 256) { n0[i] = nextS[i]; d0[i] = 1; }
    __syncthreads();
    for (int s = 0; s < 10; s++) {
        unsigned short* sn = (s & 1) ? n1 : n0;
        unsigned short* sd = (s & 1) ? d1 : d0;
        unsigned short* dn = (s & 1) ? n0 : n1;
        unsigned short* dd = (s & 1) ? d0 : d1;
        for (int i = tid; i < NPIX; i += 256) {
            unsigned nx = sn[i];
            unsigned dv = sd[i];
            if (nx != NIL) { dv += sd[nx]; nx = sn[nx]; }
            dn[i] = (unsigned short)nx;
            dd[i] = (unsigned short)dv;
        }
        __syncthreads();
    }
    for (int i = tid; i < NPIX; i += 256)
        posS[i] = (unsigned short)(NPIX - (int)d0[i]);
    __syncthreads();

    // ---- phase 2: chunked label prefix sums over leaf order; parallel per-merge dots ----
    unsigned*       P32 = (unsigned*)big;                // [1025][4] u32 (8 u16 labels SWAR)
    uint4*          P4  = (uint4*)big;
    unsigned*       scr = P32 + 4100;
    uint4*          S4  = (uint4*)scr;
    unsigned short* P16 = (unsigned short*)big;
    for (int base = 0; base < K; base += CHUNK) {
        for (int idx = tid; idx < 4100; idx += 256) P32[idx] = 0;
        __syncthreads();
        for (int i = tid; i < NPIX; i += 256) {
            unsigned l = pixLab[i];
            if (l != NIL && l >= (unsigned)base && l < (unsigned)(base + CHUNK))
                P16[(posS[i] + 1) * 8 + (l - base)] = 1;
        }
        __syncthreads();
        {   // blocked inclusive scan over rows 1..1024 (row 0 stays zero)
            int r0 = tid * 4 + 1;
            uint4 acc = P4[r0];
            for (int rr = r0 + 1; rr <= r0 + 3; rr++) { acc = add4(acc, P4[rr]); P4[rr] = acc; }
            S4[tid] = acc;
            __syncthreads();
            if (tid < 64) {   // wave-0 shuffle scan of the 256 block sums
                uint4 s0 = S4[tid * 4], s1 = S4[tid * 4 + 1], s2 = S4[tid * 4 + 2], s3 = S4[tid * 4 + 3];
                uint4 t1 = add4(s0, s1), t2 = add4(t1, s2), t3 = add4(t2, s3);
                uint4 run = t3;
                #pragma unroll
                for (int d = 1; d < 64; d <<= 1) {
                    uint4 o;
                    o.x = __shfl_up(run.x, d, 64);
                    o.y = __shfl_up(run.y, d, 64);
                    o.z = __shfl_up(run.z, d, 64);
                    o.w = __shfl_up(run.w, d, 64);
                    if (tid >= d) run = add4(run, o);
                }
                uint4 off = sub4(run, t3);   // exclusive prefix of lane totals
                S4[tid * 4]     = add4(s0, off);
                S4[tid * 4 + 1] = add4(t1, off);
                S4[tid * 4 + 2] = add4(t2, off);
                S4[tid * 4 + 3] = add4(t3, off);
            }
            __syncthreads();
            if (tid > 0) {
                uint4 off = S4[tid - 1];
                for (int rr = r0; rr <= r0 + 3; rr++) P4[rr] = add4(P4[rr], off);
            }
        }
        __syncthreads();
        for (int j = tid; j < M; j += 256) {
            unsigned recA = mRecA[j], recB = mRecB[j];
            unsigned aS = posS[recA >> 16];
            unsigned bS = posS[recA & 0xFFFFu];
            uint4 da = sub4(P4[aS + (recB >> 16)], P4[aS]);
            uint4 db = sub4(P4[bS + (recB & 0xFFFFu)], P4[bS]);
            unsigned acc;
            acc  = (da.x & 0xFFFFu) * (db.x & 0xFFFFu) + (da.x >> 16) * (db.x >> 16);
            acc += (da.y & 0xFFFFu) * (db.y & 0xFFFFu) + (da.y >> 16) * (db.y >> 16);
            acc += (da.z & 0xFFFFu) * (db.z & 0xFFFFu) + (da.z >> 16) * (db.z >> 16);
            acc += (da.w & 0xFFFFu) * (db.w & 0xFFFFu) + (da.w >> 16) * (db.w >> 16);
            commonW[j] += acc;
        }
        __syncthreads();
    }

    // ---- normalize + mask + loss ----
    if (tid == 0) { wsumSh = 0; lossSh = 0.0f; }
    __syncthreads();
    unsigned wloc = 0;
    for (int j = tid; j < M; j += 256)
        wloc += (sgn == 0) ? (mSaSb[j] - commonW[j]) : commonW[j];
    if (wloc) atomicAdd(&wsumSh, wloc);
    __syncthreads();
    const unsigned wsum = wsumSh;
    if (wsum > 0) {
        const double inv = 1.0 / (double)wsum;
        float lloc = 0.0f;
        for (int j = tid; j < M; j += 256) {
            unsigned w = (sgn == 0) ? (mSaSb[j] - commonW[j]) : commonW[j];
            if (!w) continue;
            int e = mEd[j];
            int a, b; edge_ab(e, a, b);
            int nfg = (int)(!bgS[a]) + (int)(!bgS[b]);
            bool keep = (sgn == 0) ? (nfg == 0) : (nfg >= 1);
            if (!keep) continue;
            float wn = (float)((double)w * inv);
            float fa, fb;
            if (sgn == 0) { fa = pT[a] * pT[a];            fb = pT[b] * pT[b]; }
            else { float da = 20.0f - pT[a], db = 20.0f - pT[b]; fa = da * da; fb = db * db; }
            lloc += wn * (fa + fb);
        }
        if (lloc != 0.0f) atomicAdd(&lossSh, lloc);
        __syncthreads();
        if (tid == 0 && lossSh != 0.0f) atomicAdd(out, lossSh);
    }
}

extern "C" void kernel_launch(void* const* d_in, const int* in_sizes, int n_in,
                              void* d_out, int out_size, void* d_ws, size_t ws_size,
                              hipStream_t stream) {
    const float* y_true = (const float*)d_in[0];
    const float* y_pred = (const float*)d_in[1];
    float* out = (float*)d_out;
    const int B = in_sizes[0] / (256 * 256);
    hipMemsetAsync(d_out, 0, (size_t)out_size * sizeof(float), stream);
    hipLaunchKernelGGL(malis_loss_kernel, dim3(B * 64 * 2), dim3(256), 0, stream,
                       y_true, y_pred, out);
}